// Round 11
// baseline (1184.814 us; speedup 1.0000x reference)
//
#include <hip/hip_runtime.h>
#include <hip/hip_bf16.h>
#include <cstdint>
#include <cstddef>

#define TK 8192
#define DIM 1024
#define HID 4096
#define NE 8

#define BK 64                  // K step (two 32-K halves)
#define NIT1 (DIM / BK)        // 16
#define NIT2 (HID / BK)        // 64
#define HSZ 4096               // ushorts per 32-K half (128 rows x 32)

typedef __attribute__((ext_vector_type(8))) __bf16 bfrag;
typedef __attribute__((ext_vector_type(4))) float ffrag;

static __device__ __forceinline__ ushort f2bf(float f) {
    union { float f; uint32_t u; } v; v.f = f;
    uint32_t r = (v.u + 0x7fffu + ((v.u >> 16) & 1u)) >> 16;   // RNE, finite only
    return (ushort)r;
}

static __device__ __forceinline__ uint4 pack8(float4 a, float4 b) {
    union { ushort u[8]; uint4 q; } pk;
    pk.u[0] = f2bf(a.x); pk.u[1] = f2bf(a.y); pk.u[2] = f2bf(a.z); pk.u[3] = f2bf(a.w);
    pk.u[4] = f2bf(b.x); pk.u[5] = f2bf(b.y); pk.u[6] = f2bf(b.z); pk.u[7] = f2bf(b.w);
    return pk.q;
}

static __device__ __forceinline__ void gld16(const ushort* g, ushort* l) {
    __builtin_amdgcn_global_load_lds(
        (const __attribute__((address_space(1))) unsigned int*)g,
        (__attribute__((address_space(3))) unsigned int*)l, 16, 0, 0);
}

// LDS 32-K half [128 rows][32 bf16], superblocks of 8 rows x 4 chunks(16B):
// chunk (r,kc) at 16B-slot (r>>3)*32 + kc*8 + (r&7); 0 bank conflicts (r3-r9).
// gld16 linear slot s: r = (s>>5)*8 + (s&7), kc = (s>>3)&3.
#define LDSIDX(r, kc) ((((r) >> 3) << 8) + ((kc) << 6) + (((r) & 7) << 3))
#define SLOT_R(s)  ((((s) >> 5) << 3) | ((s) & 7))
#define SLOT_KC(s) (((s) >> 3) & 3)

// ---------------- f32 -> bf16 streaming convert ----------------
__global__ __launch_bounds__(256) void k_cvt(const float* __restrict__ src,
                                             ushort* __restrict__ dst, int n8) {
    int i = blockIdx.x * blockDim.x + threadIdx.x;
    if (i >= n8) return;
    const float4* p = (const float4*)src + (size_t)i * 2;
    ((uint4*)dst)[i] = pack8(p[0], p[1]);
}

// ---------------- router: f64-accurate logits, top-2, renormalized ----------------
__global__ __launch_bounds__(256) void k_router(const float* __restrict__ x,
                                                const float* __restrict__ gw,
                                                int* __restrict__ topi, float* __restrict__ topw) {
    int t = blockIdx.x * 4 + (threadIdx.x >> 6);
    int lane = threadIdx.x & 63;
    if (t >= TK) return;
    double acc[NE];
#pragma unroll
    for (int e = 0; e < NE; ++e) acc[e] = 0.0;
    const float* xr = x + (size_t)t * DIM;
    for (int k = lane; k < DIM; k += 64) {
        double xv = (double)xr[k];
#pragma unroll
        for (int e = 0; e < NE; ++e) acc[e] += xv * (double)gw[e * DIM + k];
    }
#pragma unroll
    for (int e = 0; e < NE; ++e) {
#pragma unroll
        for (int off = 32; off > 0; off >>= 1) acc[e] += __shfl_xor(acc[e], off);
    }
    if (lane == 0) {
        int i1 = 0;
#pragma unroll
        for (int e = 1; e < NE; ++e) if (acc[e] > acc[i1]) i1 = e;
        int i2 = (i1 == 0) ? 1 : 0;
#pragma unroll
        for (int e = 0; e < NE; ++e) if (e != i1 && acc[e] > acc[i2]) i2 = e;
        double w = 1.0 / (1.0 + exp(acc[i2] - acc[i1]));
        topi[t * 2 + 0] = i1; topi[t * 2 + 1] = i2;
        topw[t * 2 + 0] = (float)w; topw[t * 2 + 1] = (float)(1.0 - w);
    }
}

__global__ void k_count(const int* __restrict__ topi, int* __restrict__ counts) {
    int i = blockIdx.x * blockDim.x + threadIdx.x;
    if (i < 2 * TK) atomicAdd(&counts[topi[i]], 1);
}

// builds per-expert offsets AND the M=128 tile descriptor list
__global__ void k_scan(const int* __restrict__ counts, int* __restrict__ offs,
                       int* __restrict__ cursor, int* __restrict__ desc,
                       int* __restrict__ ndesc) {
    if (threadIdx.x == 0 && blockIdx.x == 0) {
        int s = 0, d = 0;
        for (int e = 0; e < NE; ++e) {
            offs[e] = s; cursor[e] = s;
            int tiles = (counts[e] + 127) >> 7;
            for (int t = 0; t < tiles; ++t) desc[d++] = (e << 16) | t;
            s += counts[e];
        }
        offs[NE] = s;
        ndesc[0] = d;
    }
}

__global__ void k_scatter(const int* __restrict__ topi, const float* __restrict__ topw,
                          int* __restrict__ cursor, int* __restrict__ perm, float* __restrict__ pw) {
    int t = blockIdx.x * blockDim.x + threadIdx.x;
    if (t >= TK) return;
#pragma unroll
    for (int k = 0; k < 2; ++k) {
        int e = topi[t * 2 + k];
        int pos = atomicAdd(&cursor[e], 1);
        perm[pos] = t; pw[pos] = topw[t * 2 + k];
    }
}

// ================= m97-geometry GEMM cores =================
// 128(M) x 128(B-rows) tile, 256 threads = 4 waves (2M x 2N), per-wave 64x64.
// BK=64 as two 32-K halves; SINGLE LDS buffer (A 16KB + B 16KB = 33KB block)
// -> 4 blocks/CU; per iter: stage 8 gld16/thread, __syncthreads (full drain),
// 2x{8 ds_read + 16 MFMA}, __syncthreads. Cross-block overlap hides drains
// (m97/m114: this plain structure = 37% MfmaUtil at >=3 blocks/CU).

// ---------------- GEMM A (fused): H = silu(x@w1^T) * (x@w3^T) ----------------
// B rows interleave w1/w3 in 16-row groups -> (h1,h3) pairs wave-local.
// item = (desc, nt 0..63): 128 tokens x 64 hidden cols. items = ndesc * 64.
__global__ __launch_bounds__(256, 4) void k_ffn1(const ushort* __restrict__ xb,
                                                 const ushort* __restrict__ w1b,
                                                 const ushort* __restrict__ w3b,
                                                 const int* __restrict__ offs,
                                                 const int* __restrict__ perm,
                                                 const int* __restrict__ desc,
                                                 const int* __restrict__ ndesc_g,
                                                 ushort* __restrict__ H) {
    __shared__ ushort lA[2 * HSZ];   // 16 KiB (two 32-K halves)
    __shared__ ushort lB[2 * HSZ];   // 16 KiB
    __shared__ int lTok[128];

    const int tid = threadIdx.x;
    const int lane = tid & 63, wid = tid >> 6;
    const int l15 = lane & 15, kcc = lane >> 4;
    const int wm = (wid >> 1) * 64;
    const int wn = (wid & 1) * 64;
    const int gbase = wn >> 4;                     // 0 or 4

    const int nitems = ndesc_g[0] << 6;

    const int r0 = SLOT_R(tid), k0c = SLOT_KC(tid);
    const int r1 = SLOT_R(tid + 256), k1c = SLOT_KC(tid + 256);

    bfrag a[4], b[4];
    ffrag acc[4][4];

#pragma unroll 1
    for (int w = blockIdx.x; w < nitems; w += (int)gridDim.x) {
        __syncthreads();   // prev item fully done with LDS
        const int de = desc[w >> 6];
        const int e = de >> 16, mt = de & 0xffff, nt = w & 63;
        const int m0 = offs[e] + (mt << 7);
        const int nrows = min(128, offs[e + 1] - m0);
        if (tid < 128) lTok[tid] = (tid < nrows) ? perm[m0 + tid] : perm[m0];  // pad -> valid row, discarded
        __syncthreads();

        const ushort* pA0 = xb + (size_t)lTok[r0] * DIM + k0c * 8;
        const ushort* pA1 = xb + (size_t)lTok[r1] * DIM + k1c * 8;
        const ushort* pB0;
        const ushort* pB1;
        {
            const size_t ebase = (size_t)e * HID * DIM;
            int gg0 = r0 >> 4, gg1 = r1 >> 4;
            int h0 = nt * 64 + (((gg0 >> 1) << 4) | (r0 & 15));
            int h1 = nt * 64 + (((gg1 >> 1) << 4) | (r1 & 15));
            pB0 = ((gg0 & 1) ? w3b : w1b) + ebase + (size_t)h0 * DIM + k0c * 8;
            pB1 = ((gg1 & 1) ? w3b : w1b) + ebase + (size_t)h1 * DIM + k1c * 8;
        }

#pragma unroll
        for (int i = 0; i < 4; ++i)
#pragma unroll
            for (int j = 0; j < 4; ++j) acc[i][j] = (ffrag)0.f;

#pragma unroll 1
        for (int kt = 0; kt < NIT1; ++kt) {
            const int kb = kt * BK;
            // stage both halves of A and B (8 gld16/thread)
#pragma unroll
            for (int h = 0; h < 2; ++h) {
                gld16(pA0 + kb + h * 32, lA + h * HSZ + (wid * 64) * 8);
                gld16(pA1 + kb + h * 32, lA + h * HSZ + (256 + wid * 64) * 8);
                gld16(pB0 + kb + h * 32, lB + h * HSZ + (wid * 64) * 8);
                gld16(pB1 + kb + h * 32, lB + h * HSZ + (256 + wid * 64) * 8);
            }
            __syncthreads();   // full drain: tile resident
#pragma unroll
            for (int h = 0; h < 2; ++h) {
                const ushort* A_ = lA + h * HSZ;
                const ushort* B_ = lB + h * HSZ;
#pragma unroll
                for (int j = 0; j < 4; ++j) b[j] = *(const bfrag*)&B_[LDSIDX(wn + j * 16 + l15, kcc)];
#pragma unroll
                for (int i = 0; i < 4; ++i) a[i] = *(const bfrag*)&A_[LDSIDX(wm + i * 16 + l15, kcc)];
                __builtin_amdgcn_s_setprio(1);
#pragma unroll
                for (int i = 0; i < 4; ++i)
#pragma unroll
                    for (int j = 0; j < 4; ++j)
                        acc[i][j] = __builtin_amdgcn_mfma_f32_16x16x32_bf16(a[i], b[j], acc[i][j], 0, 0, 0);
                __builtin_amdgcn_s_setprio(0);
            }
            __syncthreads();   // reads done before next stage overwrites
        }

        // epilogue: frag pairs (jf, jf+1) = (h1, h3) for same 16 hidden cols
#pragma unroll
        for (int i = 0; i < 4; ++i) {
            int rbase = wm + i * 16 + ((lane >> 4) << 2);
#pragma unroll
            for (int q = 0; q < 4; ++q) {
                int rl = rbase + q;
                if (rl >= nrows) continue;
                size_t rowoff = (size_t)(m0 + rl) * HID;
#pragma unroll
                for (int jf = 0; jf < 4; jf += 2) {
                    int gg = gbase + jf;
                    int col = nt * 64 + ((gg >> 1) << 4) + l15;
                    float h1 = acc[i][jf][q], h3 = acc[i][jf + 1][q];
                    H[rowoff + col] = f2bf((h1 / (1.f + __expf(-h1))) * h3);
                }
            }
        }
    }
}

// ---------------- GEMM B: out[tok,:] += pw[pos] * (H[pos,:] @ w2^T) ----------------
// item = (desc, nt 0..7): 128 H-rows x 128 out cols. items = ndesc * 8.
__global__ __launch_bounds__(256, 4) void k_ffn2(const ushort* __restrict__ H,
                                                 const ushort* __restrict__ w2b,
                                                 const int* __restrict__ offs,
                                                 const int* __restrict__ perm,
                                                 const float* __restrict__ pw,
                                                 const int* __restrict__ desc,
                                                 const int* __restrict__ ndesc_g,
                                                 float* __restrict__ out) {
    __shared__ ushort lA[2 * HSZ];
    __shared__ ushort lB[2 * HSZ];
    __shared__ int lTok[128];
    __shared__ float lPw[128];

    const int tid = threadIdx.x;
    const int lane = tid & 63, wid = tid >> 6;
    const int l15 = lane & 15, kcc = lane >> 4;
    const int wm = (wid >> 1) * 64;
    const int wn = (wid & 1) * 64;

    const int nitems = ndesc_g[0] << 3;

    const int r0 = SLOT_R(tid), k0c = SLOT_KC(tid);
    const int r1 = SLOT_R(tid + 256), k1c = SLOT_KC(tid + 256);

    bfrag a[4], b[4];
    ffrag acc[4][4];

#pragma unroll 1
    for (int w = blockIdx.x; w < nitems; w += (int)gridDim.x) {
        __syncthreads();
        const int de = desc[w >> 3];
        const int e = de >> 16, mt = de & 0xffff, nt = w & 7;
        const int m0 = offs[e] + (mt << 7);
        const int nrows = min(128, offs[e + 1] - m0);
        if (tid < 128) {
            bool v = tid < nrows;
            lTok[tid] = v ? perm[m0 + tid] : 0;
            lPw[tid]  = v ? pw[m0 + tid] : 0.f;
        }
        __syncthreads();

        int p0 = m0 + r0; if (p0 > 2 * TK - 1) p0 = 2 * TK - 1;   // clamp into H
        int p1 = m0 + r1; if (p1 > 2 * TK - 1) p1 = 2 * TK - 1;
        const ushort* pA0 = H + (size_t)p0 * HID + k0c * 8;
        const ushort* pA1 = H + (size_t)p1 * HID + k1c * 8;
        const size_t ebase = (size_t)e * DIM * HID;
        const ushort* pB0 = w2b + ebase + (size_t)(nt * 128 + r0) * HID + k0c * 8;
        const ushort* pB1 = w2b + ebase + (size_t)(nt * 128 + r1) * HID + k1c * 8;

#pragma unroll
        for (int i = 0; i < 4; ++i)
#pragma unroll
            for (int j = 0; j < 4; ++j) acc[i][j] = (ffrag)0.f;

#pragma unroll 1
        for (int kt = 0; kt < NIT2; ++kt) {
            const int kb = kt * BK;
#pragma unroll
            for (int h = 0; h < 2; ++h) {
                gld16(pA0 + kb + h * 32, lA + h * HSZ + (wid * 64) * 8);
                gld16(pA1 + kb + h * 32, lA + h * HSZ + (256 + wid * 64) * 8);
                gld16(pB0 + kb + h * 32, lB + h * HSZ + (wid * 64) * 8);
                gld16(pB1 + kb + h * 32, lB + h * HSZ + (256 + wid * 64) * 8);
            }
            __syncthreads();
#pragma unroll
            for (int h = 0; h < 2; ++h) {
                const ushort* A_ = lA + h * HSZ;
                const ushort* B_ = lB + h * HSZ;
#pragma unroll
                for (int j = 0; j < 4; ++j) b[j] = *(const bfrag*)&B_[LDSIDX(wn + j * 16 + l15, kcc)];
#pragma unroll
                for (int i = 0; i < 4; ++i) a[i] = *(const bfrag*)&A_[LDSIDX(wm + i * 16 + l15, kcc)];
                __builtin_amdgcn_s_setprio(1);
#pragma unroll
                for (int i = 0; i < 4; ++i)
#pragma unroll
                    for (int j = 0; j < 4; ++j)
                        acc[i][j] = __builtin_amdgcn_mfma_f32_16x16x32_bf16(a[i], b[j], acc[i][j], 0, 0, 0);
                __builtin_amdgcn_s_setprio(0);
            }
            __syncthreads();
        }

#pragma unroll
        for (int i = 0; i < 4; ++i) {
            int rbase = wm + i * 16 + ((lane >> 4) << 2);
#pragma unroll
            for (int q = 0; q < 4; ++q) {
                int rl = rbase + q;
                if (rl >= nrows) continue;
                int tok = lTok[rl];
                float wgt = lPw[rl];
                size_t rowoff = (size_t)tok * DIM;
#pragma unroll
                for (int j = 0; j < 4; ++j) {
                    int col = nt * 128 + wn + j * 16 + l15;
                    atomicAdd(&out[rowoff + col], acc[i][j][q] * wgt);   // 2 adds/elem, deterministic
                }
            }
        }
    }
}

extern "C" void kernel_launch(void* const* d_in, const int* in_sizes, int n_in,
                              void* d_out, int out_size, void* d_ws, size_t ws_size,
                              hipStream_t stream) {
    const float* x  = (const float*)d_in[0];
    const float* gw = (const float*)d_in[1];
    const float* w1 = (const float*)d_in[2];
    const float* w2 = (const float*)d_in[3];   // dict order: x, gate_w, w1, w2, w3 !
    const float* w3 = (const float*)d_in[4];
    float* out = (float*)d_out;

    char* ws = (char*)d_ws;
    int*    topi   = (int*)(ws + 0);
    float*  topw   = (float*)(ws + 65536);
    int*    perm   = (int*)(ws + 131072);
    float*  pw     = (float*)(ws + 196608);
    int*    counts = (int*)(ws + 262144);
    int*    offs   = (int*)(ws + 262144 + 256);
    int*    cursor = (int*)(ws + 262144 + 512);
    int*    ndesc  = (int*)(ws + 262144 + 768);
    int*    desc   = (int*)(ws + 262144 + 1024);

    const size_t OFF_XB = 524288;                       // xb: 16 MiB
    const size_t OFF_H  = OFF_XB + 16777216;            // H : 128 MiB
    const size_t OFF_WA = OFF_H + 134217728;            // w1b, later w2b: 64 MiB
    const size_t OFF_WB = OFF_WA + 67108864;            // w3b: 64 MiB

    ushort* xb  = (ushort*)(ws + OFF_XB);
    ushort* H   = (ushort*)(ws + OFF_H);
    ushort* wA  = (ushort*)(ws + OFF_WA);
    ushort* wB  = (ushort*)(ws + OFF_WB);

    hipMemsetAsync(counts, 0, 32, stream);
    hipMemsetAsync(out, 0, (size_t)out_size * sizeof(float), stream);

    k_router<<<dim3(TK / 4), 256, 0, stream>>>(x, gw, topi, topw);
    k_count<<<dim3((2 * TK) / 256), 256, 0, stream>>>(topi, counts);
    k_scan<<<dim3(1), 64, 0, stream>>>(counts, offs, cursor, desc, ndesc);
    k_scatter<<<dim3(TK / 256), 256, 0, stream>>>(topi, topw, cursor, perm, pw);

    k_cvt<<<dim3((TK * DIM / 8) / 256), 256, 0, stream>>>(x, xb, TK * DIM / 8);
    k_cvt<<<dim3((NE * HID * DIM / 8) / 256), 256, 0, stream>>>(w1, wA, NE * HID * DIM / 8);
    k_cvt<<<dim3((NE * HID * DIM / 8) / 256), 256, 0, stream>>>(w3, wB, NE * HID * DIM / 8);

    k_ffn1<<<dim3(1024), 256, 0, stream>>>(xb, wA, wB, offs, perm, desc, ndesc, H);

    // w1b dead now; reuse its slot for w2b
    k_cvt<<<dim3((NE * DIM * HID / 8) / 256), 256, 0, stream>>>(w2, wA, NE * DIM * HID / 8);

    k_ffn2<<<dim3(1024), 256, 0, stream>>>(H, wA, offs, perm, pw, desc, ndesc, out);
}

// Round 12
// 1029.459 us; speedup vs baseline: 1.1509x; 1.1509x over previous
//
#include <hip/hip_runtime.h>
#include <hip/hip_bf16.h>
#include <cstdint>
#include <cstddef>

#define TK 8192
#define DIM 1024
#define HID 4096
#define NE 8

typedef __attribute__((ext_vector_type(8))) __bf16 bfrag;
typedef __attribute__((ext_vector_type(4))) float ffrag;

static __device__ __forceinline__ ushort f2bf(float f) {
    union { float f; uint32_t u; } v; v.f = f;
    uint32_t r = (v.u + 0x7fffu + ((v.u >> 16) & 1u)) >> 16;   // RNE, finite only
    return (ushort)r;
}

static __device__ __forceinline__ uint4 pack8(float4 a, float4 b) {
    union { ushort u[8]; uint4 q; } pk;
    pk.u[0] = f2bf(a.x); pk.u[1] = f2bf(a.y); pk.u[2] = f2bf(a.z); pk.u[3] = f2bf(a.w);
    pk.u[4] = f2bf(b.x); pk.u[5] = f2bf(b.y); pk.u[6] = f2bf(b.z); pk.u[7] = f2bf(b.w);
    return pk.q;
}

static __device__ __forceinline__ void gld16(const ushort* g, ushort* l) {
    __builtin_amdgcn_global_load_lds(
        (const __attribute__((address_space(1))) unsigned int*)g,
        (__attribute__((address_space(3))) unsigned int*)l, 16, 0, 0);
}

#define BARRIER() asm volatile("s_barrier" ::: "memory")
#define WAITVM(N) asm volatile("s_waitcnt vmcnt(" #N ")" ::: "memory")

// 32-K sub-region [128 rows][32 bf16], superblocks 8 rows x 4 chunks(16B):
// chunk (r,kc) at 16B-slot (r>>3)*32 + kc*8 + (r&7); 0 bank conflicts (r3-r10).
// gld16 sweep: 512 threads x 1 chunk, slot s=tid: r=(s>>5)*8+(s&7), kc=(s>>3)&3.
#define LDSIDX(r, kc) ((((r) >> 3) << 8) + ((kc) << 6) + (((r) & 7) << 3))
#define SLOT_R(s)  ((((s) >> 5) << 3) | ((s) & 7))
#define SLOT_KC(s) (((s) >> 3) & 3)

// ---------------- f32 -> bf16 streaming convert ----------------
__global__ __launch_bounds__(256) void k_cvt(const float* __restrict__ src,
                                             ushort* __restrict__ dst, int n8) {
    int i = blockIdx.x * blockDim.x + threadIdx.x;
    if (i >= n8) return;
    const float4* p = (const float4*)src + (size_t)i * 2;
    ((uint4*)dst)[i] = pack8(p[0], p[1]);
}

// ---------------- router: f64-accurate logits, top-2, renormalized ----------------
__global__ __launch_bounds__(256) void k_router(const float* __restrict__ x,
                                                const float* __restrict__ gw,
                                                int* __restrict__ topi, float* __restrict__ topw) {
    int t = blockIdx.x * 4 + (threadIdx.x >> 6);
    int lane = threadIdx.x & 63;
    if (t >= TK) return;
    double acc[NE];
#pragma unroll
    for (int e = 0; e < NE; ++e) acc[e] = 0.0;
    const float* xr = x + (size_t)t * DIM;
    for (int k = lane; k < DIM; k += 64) {
        double xv = (double)xr[k];
#pragma unroll
        for (int e = 0; e < NE; ++e) acc[e] += xv * (double)gw[e * DIM + k];
    }
#pragma unroll
    for (int e = 0; e < NE; ++e) {
#pragma unroll
        for (int off = 32; off > 0; off >>= 1) acc[e] += __shfl_xor(acc[e], off);
    }
    if (lane == 0) {
        int i1 = 0;
#pragma unroll
        for (int e = 1; e < NE; ++e) if (acc[e] > acc[i1]) i1 = e;
        int i2 = (i1 == 0) ? 1 : 0;
#pragma unroll
        for (int e = 0; e < NE; ++e) if (e != i1 && acc[e] > acc[i2]) i2 = e;
        double w = 1.0 / (1.0 + exp(acc[i2] - acc[i1]));
        topi[t * 2 + 0] = i1; topi[t * 2 + 1] = i2;
        topw[t * 2 + 0] = (float)w; topw[t * 2 + 1] = (float)(1.0 - w);
    }
}

__global__ void k_count(const int* __restrict__ topi, int* __restrict__ counts) {
    int i = blockIdx.x * blockDim.x + threadIdx.x;
    if (i < 2 * TK) atomicAdd(&counts[topi[i]], 1);
}

// per-expert offsets + M=256 desc list (ffn1) + M=128 desc list (ffn2)
__global__ void k_scan(const int* __restrict__ counts, int* __restrict__ offs,
                       int* __restrict__ cursor,
                       int* __restrict__ desc256, int* __restrict__ nd256,
                       int* __restrict__ desc128, int* __restrict__ nd128) {
    if (threadIdx.x == 0 && blockIdx.x == 0) {
        int s = 0, dA = 0, dB = 0;
        for (int e = 0; e < NE; ++e) {
            offs[e] = s; cursor[e] = s;
            int tA = (counts[e] + 255) >> 8;
            for (int t = 0; t < tA; ++t) desc256[dA++] = (e << 16) | t;
            int tB = (counts[e] + 127) >> 7;
            for (int t = 0; t < tB; ++t) desc128[dB++] = (e << 16) | t;
            s += counts[e];
        }
        offs[NE] = s;
        nd256[0] = dA; nd128[0] = dB;
    }
}

__global__ void k_scatter(const int* __restrict__ topi, const float* __restrict__ topw,
                          int* __restrict__ cursor, int* __restrict__ perm, float* __restrict__ pw) {
    int t = blockIdx.x * blockDim.x + threadIdx.x;
    if (t >= TK) return;
#pragma unroll
    for (int k = 0; k < 2; ++k) {
        int e = topi[t * 2 + k];
        int pos = atomicAdd(&cursor[e], 1);
        perm[pos] = t; pw[pos] = topw[t * 2 + k];
    }
}

// ================= 8-phase GEMM A (m201 schedule) =================
// 256 tok x 256 B-rows (interleaved w1/w3, 16-row groups -> 128 h-cols/item),
// BK=64, 8 waves (2M x 4N), per-wave 128x64, acc 8x4. 2-dbuf LDS 128 KiB:
// tile = A(2 half x 128r x 64k) + B(same). Half-tile stage = 2 gld16/thread.
// Phases P1..P8 over 2 K-tiles (t0=db0, t1=db1); stage slots (each freed by a
// preceding trailing barrier): P1 db1.A0<-t1, P2 db1.A1<-t1, P3 db0.B0<-t0+2,
// P4 db0.B1, P5 db0.A0, P6 db0.A1, P7 db1.B0<-t0+3, P8 db1.B1.
// vmcnt(4) at P4 (retires db1.A for P5 reads) and P8 (retires db0 for next P1).
// Last iter: vmcnt(0) at both. Prologue: T0 full + T1.B, vmcnt(4).
__global__ __launch_bounds__(512, 2) void k_ffn1(const ushort* __restrict__ xb,
                                                 const ushort* __restrict__ w1b,
                                                 const ushort* __restrict__ w3b,
                                                 const int* __restrict__ offs,
                                                 const int* __restrict__ perm,
                                                 const int* __restrict__ desc,
                                                 const int* __restrict__ nd_g,
                                                 ushort* __restrict__ H) {
    __shared__ ushort lA[2 * 16384];   // 64 KiB
    __shared__ ushort lB[2 * 16384];   // 64 KiB
    __shared__ int lTok[256];

    const int tid = threadIdx.x;
    const int lane = tid & 63, wid = tid >> 6;
    const int l15 = lane & 15, kcc = lane >> 4;
    const int mw = wid >> 2;                   // 0/1 -> rows mw*128
    const int wn = (wid & 3) * 64;             // B-col strip
    const int mwoff = mw * 8192;
    const int wid512 = wid * 512;

    const int NT1 = DIM / 64;                  // 16 K-tiles
    const int nitems = nd_g[0] << 5;           // 32 nt-panels per desc

    int aoff[4], boff[4];
#pragma unroll
    for (int i = 0; i < 4; ++i) aoff[i] = LDSIDX(i * 16 + l15, kcc);
#pragma unroll
    for (int j = 0; j < 4; ++j) {
        int brow = wn + j * 16 + l15;
        boff[j] = ((brow >> 7) << 13) + LDSIDX(brow & 127, kcc);
    }

    const int rS = SLOT_R(tid & 511), kcS = SLOT_KC(tid & 511);

    bfrag a[4], br[4][2];
    ffrag acc[8][4];

#pragma unroll 1
    for (int w = blockIdx.x; w < nitems; w += (int)gridDim.x) {
        __syncthreads();
        const int de = desc[w >> 5];
        const int e = de >> 16, mt = de & 0xffff, nt = w & 31;
        const int m0 = offs[e] + (mt << 8);
        const int nrows = min(256, offs[e + 1] - m0);
        if (tid < 256) lTok[tid] = (tid < nrows) ? perm[m0 + tid] : perm[m0];
        __syncthreads();

        const ushort* pA_[2]; const ushort* pB_[2];
        {
            const size_t ebase = (size_t)e * HID * DIM;
#pragma unroll
            for (int h = 0; h < 2; ++h) {
                pA_[h] = xb + (size_t)lTok[h * 128 + rS] * DIM + kcS * 8;
                int brow = h * 128 + rS;
                int gg = brow >> 4;
                int hc = nt * 128 + (((gg >> 1) << 4) | (brow & 15));
                pB_[h] = ((gg & 1) ? w3b : w1b) + ebase + (size_t)hc * DIM + kcS * 8;
            }
        }

#pragma unroll
        for (int i = 0; i < 8; ++i)
#pragma unroll
            for (int j = 0; j < 4; ++j) acc[i][j] = (ffrag)0.f;

#define SGA1(DB, HH, TT) do { if ((TT) < NT1) { \
            gld16(pA_[HH] + (TT) * 64,      lA + (DB) * 16384 + (HH) * 8192 + wid512); \
            gld16(pA_[HH] + (TT) * 64 + 32, lA + (DB) * 16384 + (HH) * 8192 + 4096 + wid512); } } while (0)
#define SGB1(DB, HH, TT) do { if ((TT) < NT1) { \
            gld16(pB_[HH] + (TT) * 64,      lB + (DB) * 16384 + (HH) * 8192 + wid512); \
            gld16(pB_[HH] + (TT) * 64 + 32, lB + (DB) * 16384 + (HH) * 8192 + 4096 + wid512); } } while (0)
#define RDB1(DB) do { _Pragma("unroll") for (int j = 0; j < 4; ++j) { \
            br[j][0] = *(const bfrag*)&lB[(DB) * 16384 + boff[j]]; \
            br[j][1] = *(const bfrag*)&lB[(DB) * 16384 + boff[j] + 4096]; } } while (0)
#define RDA1(DB, Q, S) do { _Pragma("unroll") for (int i = 0; i < 4; ++i) \
            a[i] = *(const bfrag*)&lA[(DB) * 16384 + mwoff + (S) * 4096 + (Q) * 2048 + aoff[i]]; } while (0)
#define MM1(Q, S) do { __builtin_amdgcn_s_setprio(1); \
            _Pragma("unroll") for (int i = 0; i < 4; ++i) \
            _Pragma("unroll") for (int j = 0; j < 4; ++j) \
                acc[(Q) * 4 + i][j] = __builtin_amdgcn_mfma_f32_16x16x32_bf16(a[i], br[j][S], acc[(Q) * 4 + i][j], 0, 0, 0); \
            __builtin_amdgcn_s_setprio(0); } while (0)
#define PH1(DB, Q, S, BL, STG, WT) do { \
            if (BL) RDB1(DB); RDA1(DB, Q, S); STG; WT; BARRIER(); MM1(Q, S); BARRIER(); } while (0)

        // prologue: T0 full (db0) + T1.B (db1); vmcnt(4) leaves T1.B in flight
        SGA1(0, 0, 0); SGA1(0, 1, 0); SGB1(0, 0, 0); SGB1(0, 1, 0);
        SGB1(1, 0, 1); SGB1(1, 1, 1);
        WAITVM(4);
        BARRIER();

#pragma unroll 1
        for (int it = 0; it < NT1 / 2; ++it) {
            const int t1 = 2 * it + 1, t2 = 2 * it + 2, t3 = 2 * it + 3;
            const bool last = (it == NT1 / 2 - 1);
            PH1(0, 0, 0, 1, SGA1(1, 0, t1), );
            PH1(0, 1, 0, 0, SGA1(1, 1, t1), );
            PH1(0, 0, 1, 0, SGB1(0, 0, t2), );
            PH1(0, 1, 1, 0, SGB1(0, 1, t2), if (last) { WAITVM(0); } else { WAITVM(4); });
            PH1(1, 0, 0, 1, SGA1(0, 0, t2), );
            PH1(1, 1, 0, 0, SGA1(0, 1, t2), );
            PH1(1, 0, 1, 0, SGB1(1, 0, t3), );
            PH1(1, 1, 1, 0, SGB1(1, 1, t3), if (last) { WAITVM(0); } else { WAITVM(4); });
        }
#undef PH1
#undef MM1
#undef RDA1
#undef RDB1
#undef SGB1
#undef SGA1

        // epilogue: frag pairs (jf, jf+1) = (h1, h3) for same 16 hidden cols
#pragma unroll
        for (int i = 0; i < 8; ++i) {
            int rbase = mw * 128 + i * 16 + ((lane >> 4) << 2);
#pragma unroll
            for (int q = 0; q < 4; ++q) {
                int rl = rbase + q;
                if (rl >= nrows) continue;
                size_t rowoff = (size_t)(m0 + rl) * HID;
#pragma unroll
                for (int jf = 0; jf < 4; jf += 2) {
                    int gg = (wn >> 4) + jf;
                    int col = nt * 128 + ((gg >> 1) << 4) + l15;
                    float h1 = acc[i][jf][q], h3 = acc[i][jf + 1][q];
                    H[rowoff + col] = f2bf((h1 / (1.f + __expf(-h1))) * h3);
                }
            }
        }
    }
}

// ================= 4-phase GEMM B (same ledger discipline) =================
// 128 H-rows x 256 out-cols, BK=64, 8 waves (2M x 4N), per-wave 64x64, acc 4x4.
// LDS 96 KiB: 2dbuf x (A 16K + B 32K). Sweep = 1 gld16/thread (8 KiB).
// Phases P1..P4 over 2 K-tiles; stage slots: P1 db1.B(h1,s1)+db1.A(2)<-t1,
// P2 db0.B(h0s0,h0s1,h1s0)<-t0+2, P3 db0.B(h1s1)+db0.A(2)<-t0+2,
// P4 db1.B(h0s0,h0s1,h1s0)<-t0+3. vmcnt(3) at P2 (db1 ready for P3) and P4
// (db0 ready for next P1); last iter vmcnt(0).
__global__ __launch_bounds__(512, 2) void k_ffn2(const ushort* __restrict__ Hs,
                                                 const ushort* __restrict__ w2b,
                                                 const int* __restrict__ offs,
                                                 const int* __restrict__ perm,
                                                 const float* __restrict__ pw,
                                                 const int* __restrict__ desc,
                                                 const int* __restrict__ nd_g,
                                                 float* __restrict__ out) {
    __shared__ ushort lA[2 * 8192];    // 32 KiB
    __shared__ ushort lB[2 * 16384];   // 64 KiB
    __shared__ int lTok[128];
    __shared__ float lPw[128];

    const int tid = threadIdx.x;
    const int lane = tid & 63, wid = tid >> 6;
    const int l15 = lane & 15, kcc = lane >> 4;
    const int mw = wid >> 2;                   // rows mw*64
    const int wn = (wid & 3) * 64;
    const int wid512 = wid * 512;

    const int NT2 = HID / 64;                  // 64 K-tiles
    const int nitems = nd_g[0] << 2;           // 4 nt-panels per desc

    int aoff[4], boff[4];
#pragma unroll
    for (int i = 0; i < 4; ++i) aoff[i] = LDSIDX(mw * 64 + i * 16 + l15, kcc);
#pragma unroll
    for (int j = 0; j < 4; ++j) {
        int brow = wn + j * 16 + l15;
        boff[j] = ((brow >> 7) << 13) + LDSIDX(brow & 127, kcc);
    }

    const int rS = SLOT_R(tid & 511), kcS = SLOT_KC(tid & 511);

    bfrag a[4], br[4][2];
    ffrag acc[4][4];

#pragma unroll 1
    for (int w = blockIdx.x; w < nitems; w += (int)gridDim.x) {
        __syncthreads();
        const int de = desc[w >> 2];
        const int e = de >> 16, mt = de & 0xffff, nt = w & 3;
        const int m0 = offs[e] + (mt << 7);
        const int nrows = min(128, offs[e + 1] - m0);
        if (tid < 128) {
            bool v = tid < nrows;
            lTok[tid] = v ? perm[m0 + tid] : 0;
            lPw[tid]  = v ? pw[m0 + tid] : 0.f;
        }
        __syncthreads();

        int posA = m0 + rS; if (posA > 2 * TK - 1) posA = 2 * TK - 1;
        const ushort* pA_ = Hs + (size_t)posA * HID + kcS * 8;
        const ushort* pB_[2];
        {
            const size_t ebase = (size_t)e * DIM * HID;
#pragma unroll
            for (int h = 0; h < 2; ++h)
                pB_[h] = w2b + ebase + (size_t)(nt * 256 + h * 128 + rS) * HID + kcS * 8;
        }

#pragma unroll
        for (int i = 0; i < 4; ++i)
#pragma unroll
            for (int j = 0; j < 4; ++j) acc[i][j] = (ffrag)0.f;

#define SGA2(DB, SUB, TT) do { if ((TT) < NT2) \
            gld16(pA_ + (TT) * 64 + (SUB) * 32, lA + (DB) * 8192 + (SUB) * 4096 + wid512); } while (0)
#define SGB2(DB, HH, SUB, TT) do { if ((TT) < NT2) \
            gld16(pB_[HH] + (TT) * 64 + (SUB) * 32, lB + (DB) * 16384 + (HH) * 8192 + (SUB) * 4096 + wid512); } while (0)
#define RDB2(DB) do { _Pragma("unroll") for (int j = 0; j < 4; ++j) { \
            br[j][0] = *(const bfrag*)&lB[(DB) * 16384 + boff[j]]; \
            br[j][1] = *(const bfrag*)&lB[(DB) * 16384 + boff[j] + 4096]; } } while (0)
#define RDA2(DB, S) do { _Pragma("unroll") for (int i = 0; i < 4; ++i) \
            a[i] = *(const bfrag*)&lA[(DB) * 8192 + (S) * 4096 + aoff[i]]; } while (0)
#define MM2(S) do { __builtin_amdgcn_s_setprio(1); \
            _Pragma("unroll") for (int i = 0; i < 4; ++i) \
            _Pragma("unroll") for (int j = 0; j < 4; ++j) \
                acc[i][j] = __builtin_amdgcn_mfma_f32_16x16x32_bf16(a[i], br[j][S], acc[i][j], 0, 0, 0); \
            __builtin_amdgcn_s_setprio(0); } while (0)

        // prologue: T0 full (6 sweeps) + T1.B 3 sweeps; vmcnt(3)
        SGA2(0, 0, 0); SGA2(0, 1, 0);
        SGB2(0, 0, 0, 0); SGB2(0, 0, 1, 0); SGB2(0, 1, 0, 0); SGB2(0, 1, 1, 0);
        SGB2(1, 0, 0, 1); SGB2(1, 0, 1, 1); SGB2(1, 1, 0, 1);
        WAITVM(3);
        BARRIER();

#pragma unroll 1
        for (int it = 0; it < NT2 / 2; ++it) {
            const int t1 = 2 * it + 1, t2 = 2 * it + 2, t3 = 2 * it + 3;
            const bool last = (it == NT2 / 2 - 1);
            // P1
            RDB2(0); RDA2(0, 0);
            SGB2(1, 1, 1, t1); SGA2(1, 0, t1); SGA2(1, 1, t1);
            BARRIER(); MM2(0); BARRIER();
            // P2
            RDA2(0, 1);
            SGB2(0, 0, 0, t2); SGB2(0, 0, 1, t2); SGB2(0, 1, 0, t2);
            if (last) { WAITVM(0); } else { WAITVM(3); }
            BARRIER(); MM2(1); BARRIER();
            // P3
            RDB2(1); RDA2(1, 0);
            SGB2(0, 1, 1, t2); SGA2(0, 0, t2); SGA2(0, 1, t2);
            BARRIER(); MM2(0); BARRIER();
            // P4
            RDA2(1, 1);
            SGB2(1, 0, 0, t3); SGB2(1, 0, 1, t3); SGB2(1, 1, 0, t3);
            if (last) { WAITVM(0); } else { WAITVM(3); }
            BARRIER(); MM2(1); BARRIER();
        }
#undef MM2
#undef RDA2
#undef RDB2
#undef SGB2
#undef SGA2

#pragma unroll
        for (int i = 0; i < 4; ++i) {
            int rbase = mw * 64 + i * 16 + ((lane >> 4) << 2);
#pragma unroll
            for (int q = 0; q < 4; ++q) {
                int rl = rbase + q;
                if (rl >= nrows) continue;
                int tok = lTok[rl];
                float wgt = lPw[rl];
                size_t rowoff = (size_t)tok * DIM;
#pragma unroll
                for (int j = 0; j < 4; ++j) {
                    int col = nt * 256 + wn + j * 16 + l15;
                    atomicAdd(&out[rowoff + col], acc[i][j][q] * wgt);   // 2 adds/elem, deterministic
                }
            }
        }
    }
}

extern "C" void kernel_launch(void* const* d_in, const int* in_sizes, int n_in,
                              void* d_out, int out_size, void* d_ws, size_t ws_size,
                              hipStream_t stream) {
    const float* x  = (const float*)d_in[0];
    const float* gw = (const float*)d_in[1];
    const float* w1 = (const float*)d_in[2];
    const float* w2 = (const float*)d_in[3];   // dict order: x, gate_w, w1, w2, w3 !
    const float* w3 = (const float*)d_in[4];
    float* out = (float*)d_out;

    char* ws = (char*)d_ws;
    int*    topi    = (int*)(ws + 0);
    float*  topw    = (float*)(ws + 65536);
    int*    perm    = (int*)(ws + 131072);
    float*  pw      = (float*)(ws + 196608);
    int*    counts  = (int*)(ws + 262144);
    int*    offs    = (int*)(ws + 262144 + 256);
    int*    cursor  = (int*)(ws + 262144 + 512);
    int*    nd256   = (int*)(ws + 262144 + 768);
    int*    nd128   = (int*)(ws + 262144 + 772);
    int*    desc256 = (int*)(ws + 262144 + 1024);   // <= ~80 entries
    int*    desc128 = (int*)(ws + 262144 + 2048);   // <= ~140 entries

    const size_t OFF_XB = 524288;                       // xb: 16 MiB
    const size_t OFF_H  = OFF_XB + 16777216;            // H : 128 MiB
    const size_t OFF_WA = OFF_H + 134217728;            // w1b, later w2b: 64 MiB
    const size_t OFF_WB = OFF_WA + 67108864;            // w3b: 64 MiB

    ushort* xb  = (ushort*)(ws + OFF_XB);
    ushort* H   = (ushort*)(ws + OFF_H);
    ushort* wA  = (ushort*)(ws + OFF_WA);
    ushort* wB  = (ushort*)(ws + OFF_WB);

    hipMemsetAsync(counts, 0, 32, stream);
    hipMemsetAsync(out, 0, (size_t)out_size * sizeof(float), stream);

    k_router<<<dim3(TK / 4), 256, 0, stream>>>(x, gw, topi, topw);
    k_count<<<dim3((2 * TK) / 256), 256, 0, stream>>>(topi, counts);
    k_scan<<<dim3(1), 64, 0, stream>>>(counts, offs, cursor, desc256, nd256, desc128, nd128);
    k_scatter<<<dim3(TK / 256), 256, 0, stream>>>(topi, topw, cursor, perm, pw);

    k_cvt<<<dim3((TK * DIM / 8) / 256), 256, 0, stream>>>(x, xb, TK * DIM / 8);
    k_cvt<<<dim3((NE * HID * DIM / 8) / 256), 256, 0, stream>>>(w1, wA, NE * HID * DIM / 8);
    k_cvt<<<dim3((NE * HID * DIM / 8) / 256), 256, 0, stream>>>(w3, wB, NE * HID * DIM / 8);

    k_ffn1<<<dim3(256), 512, 0, stream>>>(xb, wA, wB, offs, perm, desc256, nd256, H);

    // w1b dead now; reuse its slot for w2b
    k_cvt<<<dim3((NE * DIM * HID / 8) / 256), 256, 0, stream>>>(w2, wA, NE * DIM * HID / 8);

    k_ffn2<<<dim3(512), 512, 0, stream>>>(H, wA, offs, perm, pw, desc128, nd128, out);
}

// Round 13
// 1027.826 us; speedup vs baseline: 1.1527x; 1.0016x over previous
//
#include <hip/hip_runtime.h>
#include <hip/hip_bf16.h>
#include <cstdint>
#include <cstddef>

#define TK 8192
#define DIM 1024
#define HID 4096
#define NE 8

typedef __attribute__((ext_vector_type(8))) __bf16 bfrag;
typedef __attribute__((ext_vector_type(4))) float ffrag;

static __device__ __forceinline__ ushort f2bf(float f) {
    union { float f; uint32_t u; } v; v.f = f;
    uint32_t r = (v.u + 0x7fffu + ((v.u >> 16) & 1u)) >> 16;   // RNE, finite only
    return (ushort)r;
}

static __device__ __forceinline__ uint4 pack8(float4 a, float4 b) {
    union { ushort u[8]; uint4 q; } pk;
    pk.u[0] = f2bf(a.x); pk.u[1] = f2bf(a.y); pk.u[2] = f2bf(a.z); pk.u[3] = f2bf(a.w);
    pk.u[4] = f2bf(b.x); pk.u[5] = f2bf(b.y); pk.u[6] = f2bf(b.z); pk.u[7] = f2bf(b.w);
    return pk.q;
}

static __device__ __forceinline__ void gld16(const ushort* g, ushort* l) {
    __builtin_amdgcn_global_load_lds(
        (const __attribute__((address_space(1))) unsigned int*)g,
        (__attribute__((address_space(3))) unsigned int*)l, 16, 0, 0);
}

#define BARRIER() asm volatile("s_barrier" ::: "memory")
#define WAITVM(N) asm volatile("s_waitcnt vmcnt(" #N ")" ::: "memory")

// 32-K sub-region [128 rows][32 bf16], superblocks 8 rows x 4 chunks(16B):
// chunk (r,kc) at 16B-slot (r>>3)*32 + kc*8 + (r&7); 0 bank conflicts (r3-r10).
// gld16 sweep: 512 threads x 1 chunk, slot s=tid: r=(s>>5)*8+(s&7), kc=(s>>3)&3.
#define LDSIDX(r, kc) ((((r) >> 3) << 8) + ((kc) << 6) + (((r) & 7) << 3))
#define SLOT_R(s)  ((((s) >> 5) << 3) | ((s) & 7))
#define SLOT_KC(s) (((s) >> 3) & 3)

// ---------------- f32 -> bf16 streaming convert ----------------
__global__ __launch_bounds__(256) void k_cvt(const float* __restrict__ src,
                                             ushort* __restrict__ dst, int n8) {
    int i = blockIdx.x * blockDim.x + threadIdx.x;
    if (i >= n8) return;
    const float4* p = (const float4*)src + (size_t)i * 2;
    ((uint4*)dst)[i] = pack8(p[0], p[1]);
}

// ---------------- router: f64-accurate logits, top-2, renormalized ----------------
__global__ __launch_bounds__(256) void k_router(const float* __restrict__ x,
                                                const float* __restrict__ gw,
                                                int* __restrict__ topi, float* __restrict__ topw) {
    int t = blockIdx.x * 4 + (threadIdx.x >> 6);
    int lane = threadIdx.x & 63;
    if (t >= TK) return;
    double acc[NE];
#pragma unroll
    for (int e = 0; e < NE; ++e) acc[e] = 0.0;
    const float* xr = x + (size_t)t * DIM;
    for (int k = lane; k < DIM; k += 64) {
        double xv = (double)xr[k];
#pragma unroll
        for (int e = 0; e < NE; ++e) acc[e] += xv * (double)gw[e * DIM + k];
    }
#pragma unroll
    for (int e = 0; e < NE; ++e) {
#pragma unroll
        for (int off = 32; off > 0; off >>= 1) acc[e] += __shfl_xor(acc[e], off);
    }
    if (lane == 0) {
        int i1 = 0;
#pragma unroll
        for (int e = 1; e < NE; ++e) if (acc[e] > acc[i1]) i1 = e;
        int i2 = (i1 == 0) ? 1 : 0;
#pragma unroll
        for (int e = 0; e < NE; ++e) if (e != i1 && acc[e] > acc[i2]) i2 = e;
        double w = 1.0 / (1.0 + exp(acc[i2] - acc[i1]));
        topi[t * 2 + 0] = i1; topi[t * 2 + 1] = i2;
        topw[t * 2 + 0] = (float)w; topw[t * 2 + 1] = (float)(1.0 - w);
    }
}

__global__ void k_count(const int* __restrict__ topi, int* __restrict__ counts) {
    int i = blockIdx.x * blockDim.x + threadIdx.x;
    if (i < 2 * TK) atomicAdd(&counts[topi[i]], 1);
}

// per-expert offsets + M=256 desc list (ffn1) + M=128 desc list (ffn2)
__global__ void k_scan(const int* __restrict__ counts, int* __restrict__ offs,
                       int* __restrict__ cursor,
                       int* __restrict__ desc256, int* __restrict__ nd256,
                       int* __restrict__ desc128, int* __restrict__ nd128) {
    if (threadIdx.x == 0 && blockIdx.x == 0) {
        int s = 0, dA = 0, dB = 0;
        for (int e = 0; e < NE; ++e) {
            offs[e] = s; cursor[e] = s;
            int tA = (counts[e] + 255) >> 8;
            for (int t = 0; t < tA; ++t) desc256[dA++] = (e << 16) | t;
            int tB = (counts[e] + 127) >> 7;
            for (int t = 0; t < tB; ++t) desc128[dB++] = (e << 16) | t;
            s += counts[e];
        }
        offs[NE] = s;
        nd256[0] = dA; nd128[0] = dB;
    }
}

__global__ void k_scatter(const int* __restrict__ topi, const float* __restrict__ topw,
                          int* __restrict__ cursor, int* __restrict__ perm, float* __restrict__ pw) {
    int t = blockIdx.x * blockDim.x + threadIdx.x;
    if (t >= TK) return;
#pragma unroll
    for (int k = 0; k < 2; ++k) {
        int e = topi[t * 2 + k];
        int pos = atomicAdd(&cursor[e], 1);
        perm[pos] = t; pw[pos] = topw[t * 2 + k];
    }
}

// ================= 8-phase GEMM A (m201 schedule) =================
// 256 tok x 256 B-rows (interleaved w1/w3, 16-row groups -> 128 h-cols/item),
// BK=64, 8 waves (2M x 4N), per-wave 128x64, acc 8x4. 2-dbuf LDS 128 KiB:
// tile = A(2 half x 128r x 64k) + B(same). Half-tile stage = 2 gld16/thread.
// Phases P1..P8 over 2 K-tiles (t0=db0, t1=db1); stage slots (each freed by a
// preceding trailing barrier): P1 db1.A0<-t1, P2 db1.A1<-t1, P3 db0.B0<-t0+2,
// P4 db0.B1, P5 db0.A0, P6 db0.A1, P7 db1.B0<-t0+3, P8 db1.B1.
// vmcnt(4) at P4 (retires db1.A for P5 reads) and P8 (retires db0 for next P1).
// Last iter: vmcnt(0) at both. Prologue: T0 full + T1.B, vmcnt(4).
__global__ __launch_bounds__(512, 2) void k_ffn1(const ushort* __restrict__ xb,
                                                 const ushort* __restrict__ w1b,
                                                 const ushort* __restrict__ w3b,
                                                 const int* __restrict__ offs,
                                                 const int* __restrict__ perm,
                                                 const int* __restrict__ desc,
                                                 const int* __restrict__ nd_g,
                                                 ushort* __restrict__ H) {
    __shared__ ushort lA[2 * 16384];   // 64 KiB
    __shared__ ushort lB[2 * 16384];   // 64 KiB
    __shared__ int lTok[256];

    const int tid = threadIdx.x;
    const int lane = tid & 63, wid = tid >> 6;
    const int l15 = lane & 15, kcc = lane >> 4;
    const int mw = wid >> 2;                   // 0/1 -> rows mw*128
    const int wn = (wid & 3) * 64;             // B-col strip
    const int mwoff = mw * 8192;
    const int wid512 = wid * 512;

    const int NT1 = DIM / 64;                  // 16 K-tiles
    const int nitems = nd_g[0] << 5;           // 32 nt-panels per desc

    int aoff[4], boff[4];
#pragma unroll
    for (int i = 0; i < 4; ++i) aoff[i] = LDSIDX(i * 16 + l15, kcc);
#pragma unroll
    for (int j = 0; j < 4; ++j) {
        int brow = wn + j * 16 + l15;
        boff[j] = ((brow >> 7) << 13) + LDSIDX(brow & 127, kcc);
    }

    const int rS = SLOT_R(tid & 511), kcS = SLOT_KC(tid & 511);

    bfrag a[4], br[4][2];
    ffrag acc[8][4];

#pragma unroll 1
    for (int w = blockIdx.x; w < nitems; w += (int)gridDim.x) {
        __syncthreads();
        const int de = desc[w >> 5];
        const int e = de >> 16, mt = de & 0xffff, nt = w & 31;
        const int m0 = offs[e] + (mt << 8);
        const int nrows = min(256, offs[e + 1] - m0);
        if (tid < 256) lTok[tid] = (tid < nrows) ? perm[m0 + tid] : perm[m0];
        __syncthreads();

        const ushort* pA_[2]; const ushort* pB_[2];
        {
            const size_t ebase = (size_t)e * HID * DIM;
#pragma unroll
            for (int h = 0; h < 2; ++h) {
                pA_[h] = xb + (size_t)lTok[h * 128 + rS] * DIM + kcS * 8;
                int brow = h * 128 + rS;
                int gg = brow >> 4;
                int hc = nt * 128 + (((gg >> 1) << 4) | (brow & 15));
                pB_[h] = ((gg & 1) ? w3b : w1b) + ebase + (size_t)hc * DIM + kcS * 8;
            }
        }

#pragma unroll
        for (int i = 0; i < 8; ++i)
#pragma unroll
            for (int j = 0; j < 4; ++j) acc[i][j] = (ffrag)0.f;

#define SGA1(DB, HH, TT) do { if ((TT) < NT1) { \
            gld16(pA_[HH] + (TT) * 64,      lA + (DB) * 16384 + (HH) * 8192 + wid512); \
            gld16(pA_[HH] + (TT) * 64 + 32, lA + (DB) * 16384 + (HH) * 8192 + 4096 + wid512); } } while (0)
#define SGB1(DB, HH, TT) do { if ((TT) < NT1) { \
            gld16(pB_[HH] + (TT) * 64,      lB + (DB) * 16384 + (HH) * 8192 + wid512); \
            gld16(pB_[HH] + (TT) * 64 + 32, lB + (DB) * 16384 + (HH) * 8192 + 4096 + wid512); } } while (0)
#define RDB1(DB) do { _Pragma("unroll") for (int j = 0; j < 4; ++j) { \
            br[j][0] = *(const bfrag*)&lB[(DB) * 16384 + boff[j]]; \
            br[j][1] = *(const bfrag*)&lB[(DB) * 16384 + boff[j] + 4096]; } } while (0)
#define RDA1(DB, Q, S) do { _Pragma("unroll") for (int i = 0; i < 4; ++i) \
            a[i] = *(const bfrag*)&lA[(DB) * 16384 + mwoff + (S) * 4096 + (Q) * 2048 + aoff[i]]; } while (0)
#define MM1(Q, S) do { __builtin_amdgcn_s_setprio(1); \
            _Pragma("unroll") for (int i = 0; i < 4; ++i) \
            _Pragma("unroll") for (int j = 0; j < 4; ++j) \
                acc[(Q) * 4 + i][j] = __builtin_amdgcn_mfma_f32_16x16x32_bf16(a[i], br[j][S], acc[(Q) * 4 + i][j], 0, 0, 0); \
            __builtin_amdgcn_s_setprio(0); } while (0)
#define PH1(DB, Q, S, BL, STG, WT) do { \
            if (BL) RDB1(DB); RDA1(DB, Q, S); STG; WT; BARRIER(); MM1(Q, S); BARRIER(); } while (0)

        // prologue: T0 full (db0) + T1.B (db1); vmcnt(4) leaves T1.B in flight
        SGA1(0, 0, 0); SGA1(0, 1, 0); SGB1(0, 0, 0); SGB1(0, 1, 0);
        SGB1(1, 0, 1); SGB1(1, 1, 1);
        WAITVM(4);
        BARRIER();

#pragma unroll 1
        for (int it = 0; it < NT1 / 2; ++it) {
            const int t1 = 2 * it + 1, t2 = 2 * it + 2, t3 = 2 * it + 3;
            const bool last = (it == NT1 / 2 - 1);
            PH1(0, 0, 0, 1, SGA1(1, 0, t1), );
            PH1(0, 1, 0, 0, SGA1(1, 1, t1), );
            PH1(0, 0, 1, 0, SGB1(0, 0, t2), );
            PH1(0, 1, 1, 0, SGB1(0, 1, t2), if (last) { WAITVM(0); } else { WAITVM(4); });
            PH1(1, 0, 0, 1, SGA1(0, 0, t2), );
            PH1(1, 1, 0, 0, SGA1(0, 1, t2), );
            PH1(1, 0, 1, 0, SGB1(1, 0, t3), );
            PH1(1, 1, 1, 0, SGB1(1, 1, t3), if (last) { WAITVM(0); } else { WAITVM(4); });
        }
#undef PH1
#undef MM1
#undef RDA1
#undef RDB1
#undef SGB1
#undef SGA1

        // epilogue: frag pairs (jf, jf+1) = (h1, h3) for same 16 hidden cols
#pragma unroll
        for (int i = 0; i < 8; ++i) {
            int rbase = mw * 128 + i * 16 + ((lane >> 4) << 2);
#pragma unroll
            for (int q = 0; q < 4; ++q) {
                int rl = rbase + q;
                if (rl >= nrows) continue;
                size_t rowoff = (size_t)(m0 + rl) * HID;
#pragma unroll
                for (int jf = 0; jf < 4; jf += 2) {
                    int gg = (wn >> 4) + jf;
                    int col = nt * 128 + ((gg >> 1) << 4) + l15;
                    float h1 = acc[i][jf][q], h3 = acc[i][jf + 1][q];
                    H[rowoff + col] = f2bf((h1 / (1.f + __expf(-h1))) * h3);
                }
            }
        }
    }
}

// ================= 4-phase GEMM B (same ledger discipline) =================
// 128 H-rows x 256 out-cols, BK=64, 8 waves (2M x 4N), per-wave 64x64, acc 4x4.
// LDS 96 KiB: 2dbuf x (A 16K + B 32K). Sweep = 1 gld16/thread (8 KiB).
// Phases P1..P4 over 2 K-tiles; stage slots: P1 db1.B(h1,s1)+db1.A(2)<-t1,
// P2 db0.B(h0s0,h0s1,h1s0)<-t0+2, P3 db0.B(h1s1)+db0.A(2)<-t0+2,
// P4 db1.B(h0s0,h0s1,h1s0)<-t0+3. vmcnt(3) at P2 (db1 ready for P3) and P4
// (db0 ready for next P1); last iter vmcnt(0).
__global__ __launch_bounds__(512, 2) void k_ffn2(const ushort* __restrict__ Hs,
                                                 const ushort* __restrict__ w2b,
                                                 const int* __restrict__ offs,
                                                 const int* __restrict__ perm,
                                                 const float* __restrict__ pw,
                                                 const int* __restrict__ desc,
                                                 const int* __restrict__ nd_g,
                                                 float* __restrict__ out) {
    __shared__ ushort lA[2 * 8192];    // 32 KiB
    __shared__ ushort lB[2 * 16384];   // 64 KiB
    __shared__ int lTok[128];
    __shared__ float lPw[128];

    const int tid = threadIdx.x;
    const int lane = tid & 63, wid = tid >> 6;
    const int l15 = lane & 15, kcc = lane >> 4;
    const int mw = wid >> 2;                   // rows mw*64
    const int wn = (wid & 3) * 64;
    const int wid512 = wid * 512;

    const int NT2 = HID / 64;                  // 64 K-tiles
    const int nitems = nd_g[0] << 2;           // 4 nt-panels per desc

    int aoff[4], boff[4];
#pragma unroll
    for (int i = 0; i < 4; ++i) aoff[i] = LDSIDX(mw * 64 + i * 16 + l15, kcc);
#pragma unroll
    for (int j = 0; j < 4; ++j) {
        int brow = wn + j * 16 + l15;
        boff[j] = ((brow >> 7) << 13) + LDSIDX(brow & 127, kcc);
    }

    const int rS = SLOT_R(tid & 511), kcS = SLOT_KC(tid & 511);

    bfrag a[4], br[4][2];
    ffrag acc[4][4];

#pragma unroll 1
    for (int w = blockIdx.x; w < nitems; w += (int)gridDim.x) {
        __syncthreads();
        const int de = desc[w >> 2];
        const int e = de >> 16, mt = de & 0xffff, nt = w & 3;
        const int m0 = offs[e] + (mt << 7);
        const int nrows = min(128, offs[e + 1] - m0);
        if (tid < 128) {
            bool v = tid < nrows;
            lTok[tid] = v ? perm[m0 + tid] : 0;
            lPw[tid]  = v ? pw[m0 + tid] : 0.f;
        }
        __syncthreads();

        int posA = m0 + rS; if (posA > 2 * TK - 1) posA = 2 * TK - 1;
        const ushort* pA_ = Hs + (size_t)posA * HID + kcS * 8;
        const ushort* pB_[2];
        {
            const size_t ebase = (size_t)e * DIM * HID;
#pragma unroll
            for (int h = 0; h < 2; ++h)
                pB_[h] = w2b + ebase + (size_t)(nt * 256 + h * 128 + rS) * HID + kcS * 8;
        }

#pragma unroll
        for (int i = 0; i < 4; ++i)
#pragma unroll
            for (int j = 0; j < 4; ++j) acc[i][j] = (ffrag)0.f;

#define SGA2(DB, SUB, TT) do { if ((TT) < NT2) \
            gld16(pA_ + (TT) * 64 + (SUB) * 32, lA + (DB) * 8192 + (SUB) * 4096 + wid512); } while (0)
#define SGB2(DB, HH, SUB, TT) do { if ((TT) < NT2) \
            gld16(pB_[HH] + (TT) * 64 + (SUB) * 32, lB + (DB) * 16384 + (HH) * 8192 + (SUB) * 4096 + wid512); } while (0)
#define RDB2(DB) do { _Pragma("unroll") for (int j = 0; j < 4; ++j) { \
            br[j][0] = *(const bfrag*)&lB[(DB) * 16384 + boff[j]]; \
            br[j][1] = *(const bfrag*)&lB[(DB) * 16384 + boff[j] + 4096]; } } while (0)
#define RDA2(DB, S) do { _Pragma("unroll") for (int i = 0; i < 4; ++i) \
            a[i] = *(const bfrag*)&lA[(DB) * 8192 + (S) * 4096 + aoff[i]]; } while (0)
#define MM2(S) do { __builtin_amdgcn_s_setprio(1); \
            _Pragma("unroll") for (int i = 0; i < 4; ++i) \
            _Pragma("unroll") for (int j = 0; j < 4; ++j) \
                acc[i][j] = __builtin_amdgcn_mfma_f32_16x16x32_bf16(a[i], br[j][S], acc[i][j], 0, 0, 0); \
            __builtin_amdgcn_s_setprio(0); } while (0)

        // prologue: T0 full (6 sweeps) + T1.B 3 sweeps; vmcnt(3)
        SGA2(0, 0, 0); SGA2(0, 1, 0);
        SGB2(0, 0, 0, 0); SGB2(0, 0, 1, 0); SGB2(0, 1, 0, 0); SGB2(0, 1, 1, 0);
        SGB2(1, 0, 0, 1); SGB2(1, 0, 1, 1); SGB2(1, 1, 0, 1);
        WAITVM(3);
        BARRIER();

#pragma unroll 1
        for (int it = 0; it < NT2 / 2; ++it) {
            const int t1 = 2 * it + 1, t2 = 2 * it + 2, t3 = 2 * it + 3;
            const bool last = (it == NT2 / 2 - 1);
            // P1
            RDB2(0); RDA2(0, 0);
            SGB2(1, 1, 1, t1); SGA2(1, 0, t1); SGA2(1, 1, t1);
            BARRIER(); MM2(0); BARRIER();
            // P2
            RDA2(0, 1);
            SGB2(0, 0, 0, t2); SGB2(0, 0, 1, t2); SGB2(0, 1, 0, t2);
            if (last) { WAITVM(0); } else { WAITVM(3); }
            BARRIER(); MM2(1); BARRIER();
            // P3
            RDB2(1); RDA2(1, 0);
            SGB2(0, 1, 1, t2); SGA2(0, 0, t2); SGA2(0, 1, t2);
            BARRIER(); MM2(0); BARRIER();
            // P4
            RDA2(1, 1);
            SGB2(1, 0, 0, t3); SGB2(1, 0, 1, t3); SGB2(1, 1, 0, t3);
            if (last) { WAITVM(0); } else { WAITVM(3); }
            BARRIER(); MM2(1); BARRIER();
        }
#undef MM2
#undef RDA2
#undef RDB2
#undef SGB2
#undef SGA2

#pragma unroll
        for (int i = 0; i < 4; ++i) {
            int rbase = mw * 64 + i * 16 + ((lane >> 4) << 2);
#pragma unroll
            for (int q = 0; q < 4; ++q) {
                int rl = rbase + q;
                if (rl >= nrows) continue;
                int tok = lTok[rl];
                float wgt = lPw[rl];
                size_t rowoff = (size_t)tok * DIM;
#pragma unroll
                for (int j = 0; j < 4; ++j) {
                    int col = nt * 256 + wn + j * 16 + l15;
                    atomicAdd(&out[rowoff + col], acc[i][j][q] * wgt);   // 2 adds/elem, deterministic
                }
            }
        }
    }
}

extern "C" void kernel_launch(void* const* d_in, const int* in_sizes, int n_in,
                              void* d_out, int out_size, void* d_ws, size_t ws_size,
                              hipStream_t stream) {
    const float* x  = (const float*)d_in[0];
    const float* gw = (const float*)d_in[1];
    const float* w1 = (const float*)d_in[2];
    const float* w2 = (const float*)d_in[3];   // dict order: x, gate_w, w1, w2, w3 !
    const float* w3 = (const float*)d_in[4];
    float* out = (float*)d_out;

    char* ws = (char*)d_ws;
    int*    topi    = (int*)(ws + 0);
    float*  topw    = (float*)(ws + 65536);
    int*    perm    = (int*)(ws + 131072);
    float*  pw      = (float*)(ws + 196608);
    int*    counts  = (int*)(ws + 262144);
    int*    offs    = (int*)(ws + 262144 + 256);
    int*    cursor  = (int*)(ws + 262144 + 512);
    int*    nd256   = (int*)(ws + 262144 + 768);
    int*    nd128   = (int*)(ws + 262144 + 772);
    int*    desc256 = (int*)(ws + 262144 + 1024);   // <= ~80 entries
    int*    desc128 = (int*)(ws + 262144 + 2048);   // <= ~140 entries

    const size_t OFF_XB = 524288;                       // xb: 16 MiB
    const size_t OFF_H  = OFF_XB + 16777216;            // H : 128 MiB
    const size_t OFF_WA = OFF_H + 134217728;            // w1b, later w2b: 64 MiB
    const size_t OFF_WB = OFF_WA + 67108864;            // w3b: 64 MiB

    ushort* xb  = (ushort*)(ws + OFF_XB);
    ushort* H   = (ushort*)(ws + OFF_H);
    ushort* wA  = (ushort*)(ws + OFF_WA);
    ushort* wB  = (ushort*)(ws + OFF_WB);

    hipMemsetAsync(counts, 0, 32, stream);
    hipMemsetAsync(out, 0, (size_t)out_size * sizeof(float), stream);

    k_router<<<dim3(TK / 4), 256, 0, stream>>>(x, gw, topi, topw);
    k_count<<<dim3((2 * TK) / 256), 256, 0, stream>>>(topi, counts);
    k_scan<<<dim3(1), 64, 0, stream>>>(counts, offs, cursor, desc256, nd256, desc128, nd128);
    k_scatter<<<dim3(TK / 256), 256, 0, stream>>>(topi, topw, cursor, perm, pw);

    k_cvt<<<dim3((TK * DIM / 8) / 256), 256, 0, stream>>>(x, xb, TK * DIM / 8);
    k_cvt<<<dim3((NE * HID * DIM / 8) / 256), 256, 0, stream>>>(w1, wA, NE * HID * DIM / 8);
    k_cvt<<<dim3((NE * HID * DIM / 8) / 256), 256, 0, stream>>>(w3, wB, NE * HID * DIM / 8);

    k_ffn1<<<dim3(256), 512, 0, stream>>>(xb, wA, wB, offs, perm, desc256, nd256, H);

    // w1b dead now; reuse its slot for w2b
    k_cvt<<<dim3((NE * DIM * HID / 8) / 256), 256, 0, stream>>>(w2, wA, NE * DIM * HID / 8);

    k_ffn2<<<dim3(512), 512, 0, stream>>>(H, wA, offs, perm, pw, desc128, nd128, out);
}

// Round 14
// 1004.501 us; speedup vs baseline: 1.1795x; 1.0232x over previous
//
#include <hip/hip_runtime.h>
#include <hip/hip_bf16.h>
#include <cstdint>
#include <cstddef>

#define TK 8192
#define DIM 1024
#define HID 4096
#define NE 8

typedef __attribute__((ext_vector_type(8))) __bf16 bfrag;
typedef __attribute__((ext_vector_type(4))) float ffrag;

static __device__ __forceinline__ ushort f2bf(float f) {
    union { float f; uint32_t u; } v; v.f = f;
    uint32_t r = (v.u + 0x7fffu + ((v.u >> 16) & 1u)) >> 16;   // RNE, finite only
    return (ushort)r;
}

static __device__ __forceinline__ uint4 pack8(float4 a, float4 b) {
    union { ushort u[8]; uint4 q; } pk;
    pk.u[0] = f2bf(a.x); pk.u[1] = f2bf(a.y); pk.u[2] = f2bf(a.z); pk.u[3] = f2bf(a.w);
    pk.u[4] = f2bf(b.x); pk.u[5] = f2bf(b.y); pk.u[6] = f2bf(b.z); pk.u[7] = f2bf(b.w);
    return pk.q;
}

static __device__ __forceinline__ void gld16(const ushort* g, ushort* l) {
    __builtin_amdgcn_global_load_lds(
        (const __attribute__((address_space(1))) unsigned int*)g,
        (__attribute__((address_space(3))) unsigned int*)l, 16, 0, 0);
}

#define BARRIER() asm volatile("s_barrier" ::: "memory")
#define WAITVM(N) asm volatile("s_waitcnt vmcnt(" #N ")" ::: "memory")

// 32-K sub-region [128 rows][32 bf16], superblocks 8 rows x 4 chunks(16B):
// chunk (r,kc) at 16B-slot (r>>3)*32 + kc*8 + (r&7); 0 bank conflicts (r3-r11).
// gld16 sweep: 512 threads x 1 chunk, slot s=tid: r=(s>>5)*8+(s&7), kc=(s>>3)&3.
#define LDSIDX(r, kc) ((((r) >> 3) << 8) + ((kc) << 6) + (((r) & 7) << 3))
#define SLOT_R(s)  ((((s) >> 5) << 3) | ((s) & 7))
#define SLOT_KC(s) (((s) >> 3) & 3)

// ---------------- f32 -> bf16 streaming convert ----------------
__global__ __launch_bounds__(256) void k_cvt(const float* __restrict__ src,
                                             ushort* __restrict__ dst, int n8) {
    int i = blockIdx.x * blockDim.x + threadIdx.x;
    if (i >= n8) return;
    const float4* p = (const float4*)src + (size_t)i * 2;
    ((uint4*)dst)[i] = pack8(p[0], p[1]);
}

// ---------------- router: f64-accurate logits, top-2, renormalized ----------------
__global__ __launch_bounds__(256) void k_router(const float* __restrict__ x,
                                                const float* __restrict__ gw,
                                                int* __restrict__ topi, float* __restrict__ topw) {
    int t = blockIdx.x * 4 + (threadIdx.x >> 6);
    int lane = threadIdx.x & 63;
    if (t >= TK) return;
    double acc[NE];
#pragma unroll
    for (int e = 0; e < NE; ++e) acc[e] = 0.0;
    const float* xr = x + (size_t)t * DIM;
    for (int k = lane; k < DIM; k += 64) {
        double xv = (double)xr[k];
#pragma unroll
        for (int e = 0; e < NE; ++e) acc[e] += xv * (double)gw[e * DIM + k];
    }
#pragma unroll
    for (int e = 0; e < NE; ++e) {
#pragma unroll
        for (int off = 32; off > 0; off >>= 1) acc[e] += __shfl_xor(acc[e], off);
    }
    if (lane == 0) {
        int i1 = 0;
#pragma unroll
        for (int e = 1; e < NE; ++e) if (acc[e] > acc[i1]) i1 = e;
        int i2 = (i1 == 0) ? 1 : 0;
#pragma unroll
        for (int e = 0; e < NE; ++e) if (e != i1 && acc[e] > acc[i2]) i2 = e;
        double w = 1.0 / (1.0 + exp(acc[i2] - acc[i1]));
        topi[t * 2 + 0] = i1; topi[t * 2 + 1] = i2;
        topw[t * 2 + 0] = (float)w; topw[t * 2 + 1] = (float)(1.0 - w);
    }
}

__global__ void k_count(const int* __restrict__ topi, int* __restrict__ counts) {
    int i = blockIdx.x * blockDim.x + threadIdx.x;
    if (i < 2 * TK) atomicAdd(&counts[topi[i]], 1);
}

// per-expert offsets + M=256 desc list (ffn1) + M=128 desc list (ffn2)
__global__ void k_scan(const int* __restrict__ counts, int* __restrict__ offs,
                       int* __restrict__ cursor,
                       int* __restrict__ desc256, int* __restrict__ nd256,
                       int* __restrict__ desc128, int* __restrict__ nd128) {
    if (threadIdx.x == 0 && blockIdx.x == 0) {
        int s = 0, dA = 0, dB = 0;
        for (int e = 0; e < NE; ++e) {
            offs[e] = s; cursor[e] = s;
            int tA = (counts[e] + 255) >> 8;
            for (int t = 0; t < tA; ++t) desc256[dA++] = (e << 16) | t;
            int tB = (counts[e] + 127) >> 7;
            for (int t = 0; t < tB; ++t) desc128[dB++] = (e << 16) | t;
            s += counts[e];
        }
        offs[NE] = s;
        nd256[0] = dA; nd128[0] = dB;
    }
}

__global__ void k_scatter(const int* __restrict__ topi, const float* __restrict__ topw,
                          int* __restrict__ cursor, int* __restrict__ perm,
                          float* __restrict__ pw, int* __restrict__ tokslot) {
    int t = blockIdx.x * blockDim.x + threadIdx.x;
    if (t >= TK) return;
#pragma unroll
    for (int k = 0; k < 2; ++k) {
        int e = topi[t * 2 + k];
        int pos = atomicAdd(&cursor[e], 1);
        perm[pos] = t; pw[pos] = topw[t * 2 + k];
        tokslot[t * 2 + k] = pos;
    }
}

// ---------------- combine: out[t] = pw[s0]*H2[s0] + pw[s1]*H2[s1] ----------------
__global__ __launch_bounds__(256) void k_combine(const float* __restrict__ H2,
                                                 const int* __restrict__ tokslot,
                                                 const float* __restrict__ pw,
                                                 float* __restrict__ out) {
    const int t = blockIdx.x, d = threadIdx.x;          // 8192 x 256 float4
    const int s0 = tokslot[t * 2], s1 = tokslot[t * 2 + 1];
    const float w0 = pw[s0], w1 = pw[s1];
    float4 va = ((const float4*)(H2 + (size_t)s0 * DIM))[d];
    float4 vb = ((const float4*)(H2 + (size_t)s1 * DIM))[d];
    float4 r;
    r.x = w0 * va.x + w1 * vb.x;
    r.y = w0 * va.y + w1 * vb.y;
    r.z = w0 * va.z + w1 * vb.z;
    r.w = w0 * va.w + w1 * vb.w;
    ((float4*)(out + (size_t)t * DIM))[d] = r;
}

// ================= 8-phase GEMM A (m201 schedule, R11-verified) =================
// 256 tok x 256 B-rows (interleaved w1/w3 -> 128 h-cols/item), BK=64, 8 waves
// (2M x 4N), per-wave 128x64, acc 8x4. 2-dbuf LDS 128 KiB. vmcnt(4) at P4/P8
// only; last iter vmcnt(0). One item per block; XCD-pinned decode:
// b = q*256 + nt*8 + r  ->  desc d = q*8+r (all 32 nt-items of d on XCD r).
__global__ __launch_bounds__(512, 2) void k_ffn1(const ushort* __restrict__ xb,
                                                 const ushort* __restrict__ w1b,
                                                 const ushort* __restrict__ w3b,
                                                 const int* __restrict__ offs,
                                                 const int* __restrict__ perm,
                                                 const int* __restrict__ desc,
                                                 const int* __restrict__ nd_g,
                                                 ushort* __restrict__ H) {
    const int b = blockIdx.x;
    const int d = ((b >> 8) << 3) | (b & 7);
    const int nt = (b >> 3) & 31;
    if (d >= nd_g[0]) return;

    __shared__ ushort lA[2 * 16384];   // 64 KiB
    __shared__ ushort lB[2 * 16384];   // 64 KiB
    __shared__ int lTok[256];

    const int tid = threadIdx.x;
    const int lane = tid & 63, wid = tid >> 6;
    const int l15 = lane & 15, kcc = lane >> 4;
    const int mw = wid >> 2;
    const int wn = (wid & 3) * 64;
    const int mwoff = mw * 8192;
    const int wid512 = wid * 512;

    const int NT1 = DIM / 64;                  // 16 K-tiles

    int aoff[4], boff[4];
#pragma unroll
    for (int i = 0; i < 4; ++i) aoff[i] = LDSIDX(i * 16 + l15, kcc);
#pragma unroll
    for (int j = 0; j < 4; ++j) {
        int brow = wn + j * 16 + l15;
        boff[j] = ((brow >> 7) << 13) + LDSIDX(brow & 127, kcc);
    }

    const int rS = SLOT_R(tid & 511), kcS = SLOT_KC(tid & 511);

    bfrag a[4], br[4][2];
    ffrag acc[8][4];

    const int de = desc[d];
    const int e = de >> 16, mt = de & 0xffff;
    const int m0 = offs[e] + (mt << 8);
    const int nrows = min(256, offs[e + 1] - m0);
    if (tid < 256) lTok[tid] = (tid < nrows) ? perm[m0 + tid] : perm[m0];
    __syncthreads();

    const ushort* pA_[2]; const ushort* pB_[2];
    {
        const size_t ebase = (size_t)e * HID * DIM;
#pragma unroll
        for (int h = 0; h < 2; ++h) {
            pA_[h] = xb + (size_t)lTok[h * 128 + rS] * DIM + kcS * 8;
            int brow = h * 128 + rS;
            int gg = brow >> 4;
            int hc = nt * 128 + (((gg >> 1) << 4) | (brow & 15));
            pB_[h] = ((gg & 1) ? w3b : w1b) + ebase + (size_t)hc * DIM + kcS * 8;
        }
    }

#pragma unroll
    for (int i = 0; i < 8; ++i)
#pragma unroll
        for (int j = 0; j < 4; ++j) acc[i][j] = (ffrag)0.f;

#define SGA1(DB, HH, TT) do { if ((TT) < NT1) { \
        gld16(pA_[HH] + (TT) * 64,      lA + (DB) * 16384 + (HH) * 8192 + wid512); \
        gld16(pA_[HH] + (TT) * 64 + 32, lA + (DB) * 16384 + (HH) * 8192 + 4096 + wid512); } } while (0)
#define SGB1(DB, HH, TT) do { if ((TT) < NT1) { \
        gld16(pB_[HH] + (TT) * 64,      lB + (DB) * 16384 + (HH) * 8192 + wid512); \
        gld16(pB_[HH] + (TT) * 64 + 32, lB + (DB) * 16384 + (HH) * 8192 + 4096 + wid512); } } while (0)
#define RDB1(DB) do { _Pragma("unroll") for (int j = 0; j < 4; ++j) { \
        br[j][0] = *(const bfrag*)&lB[(DB) * 16384 + boff[j]]; \
        br[j][1] = *(const bfrag*)&lB[(DB) * 16384 + boff[j] + 4096]; } } while (0)
#define RDA1(DB, Q, S) do { _Pragma("unroll") for (int i = 0; i < 4; ++i) \
        a[i] = *(const bfrag*)&lA[(DB) * 16384 + mwoff + (S) * 4096 + (Q) * 2048 + aoff[i]]; } while (0)
#define MM1(Q, S) do { __builtin_amdgcn_s_setprio(1); \
        _Pragma("unroll") for (int i = 0; i < 4; ++i) \
        _Pragma("unroll") for (int j = 0; j < 4; ++j) \
            acc[(Q) * 4 + i][j] = __builtin_amdgcn_mfma_f32_16x16x32_bf16(a[i], br[j][S], acc[(Q) * 4 + i][j], 0, 0, 0); \
        __builtin_amdgcn_s_setprio(0); } while (0)
#define PH1(DB, Q, S, BL, STG, WT) do { \
        if (BL) RDB1(DB); RDA1(DB, Q, S); STG; WT; BARRIER(); MM1(Q, S); BARRIER(); } while (0)

    // prologue: T0 full (db0) + T1.B (db1); vmcnt(4) leaves T1.B in flight
    SGA1(0, 0, 0); SGA1(0, 1, 0); SGB1(0, 0, 0); SGB1(0, 1, 0);
    SGB1(1, 0, 1); SGB1(1, 1, 1);
    WAITVM(4);
    BARRIER();

#pragma unroll 1
    for (int it = 0; it < NT1 / 2; ++it) {
        const int t1 = 2 * it + 1, t2 = 2 * it + 2, t3 = 2 * it + 3;
        const bool last = (it == NT1 / 2 - 1);
        PH1(0, 0, 0, 1, SGA1(1, 0, t1), );
        PH1(0, 1, 0, 0, SGA1(1, 1, t1), );
        PH1(0, 0, 1, 0, SGB1(0, 0, t2), );
        PH1(0, 1, 1, 0, SGB1(0, 1, t2), if (last) { WAITVM(0); } else { WAITVM(4); });
        PH1(1, 0, 0, 1, SGA1(0, 0, t2), );
        PH1(1, 1, 0, 0, SGA1(0, 1, t2), );
        PH1(1, 0, 1, 0, SGB1(1, 0, t3), );
        PH1(1, 1, 1, 0, SGB1(1, 1, t3), if (last) { WAITVM(0); } else { WAITVM(4); });
    }
#undef PH1
#undef MM1
#undef RDA1
#undef RDB1
#undef SGB1
#undef SGA1

    // epilogue: frag pairs (jf, jf+1) = (h1, h3) for same 16 hidden cols
#pragma unroll
    for (int i = 0; i < 8; ++i) {
        int rbase = mw * 128 + i * 16 + ((lane >> 4) << 2);
#pragma unroll
        for (int q = 0; q < 4; ++q) {
            int rl = rbase + q;
            if (rl >= nrows) continue;
            size_t rowoff = (size_t)(m0 + rl) * HID;
#pragma unroll
            for (int jf = 0; jf < 4; jf += 2) {
                int gg = (wn >> 4) + jf;
                int col = nt * 128 + ((gg >> 1) << 4) + l15;
                float h1 = acc[i][jf][q], h3 = acc[i][jf + 1][q];
                H[rowoff + col] = f2bf((h1 / (1.f + __expf(-h1))) * h3);
            }
        }
    }
}

// ================= 4-phase GEMM B (R11-verified core; partials out) =================
// 128 H-rows x 256 out-cols, per-wave 64x64. Writes f32 partials H2[pos,:]
// (no atomics; combine applies routing weights). One item per block;
// XCD-pinned decode: b = q*32 + nt*8 + r -> desc d = q*8+r (4 nt-items of
// one H-panel share XCD r).
__global__ __launch_bounds__(512, 2) void k_ffn2(const ushort* __restrict__ Hs,
                                                 const ushort* __restrict__ w2b,
                                                 const int* __restrict__ offs,
                                                 const int* __restrict__ desc,
                                                 const int* __restrict__ nd_g,
                                                 float* __restrict__ H2) {
    const int b = blockIdx.x;
    const int d = ((b >> 5) << 3) | (b & 7);
    const int nt = (b >> 3) & 3;
    if (d >= nd_g[0]) return;

    __shared__ ushort lA[2 * 8192];    // 32 KiB
    __shared__ ushort lB[2 * 16384];   // 64 KiB

    const int tid = threadIdx.x;
    const int lane = tid & 63, wid = tid >> 6;
    const int l15 = lane & 15, kcc = lane >> 4;
    const int mw = wid >> 2;
    const int wn = (wid & 3) * 64;
    const int wid512 = wid * 512;

    const int NT2 = HID / 64;                  // 64 K-tiles

    int aoff[4], boff[4];
#pragma unroll
    for (int i = 0; i < 4; ++i) aoff[i] = LDSIDX(mw * 64 + i * 16 + l15, kcc);
#pragma unroll
    for (int j = 0; j < 4; ++j) {
        int brow = wn + j * 16 + l15;
        boff[j] = ((brow >> 7) << 13) + LDSIDX(brow & 127, kcc);
    }

    const int rS = SLOT_R(tid & 511), kcS = SLOT_KC(tid & 511);

    bfrag a[4], br[4][2];
    ffrag acc[4][4];

    const int de = desc[d];
    const int e = de >> 16, mt = de & 0xffff;
    const int m0 = offs[e] + (mt << 7);
    const int nrows = min(128, offs[e + 1] - m0);

    int posA = m0 + rS; if (posA > 2 * TK - 1) posA = 2 * TK - 1;
    const ushort* pA_ = Hs + (size_t)posA * HID + kcS * 8;
    const ushort* pB_[2];
    {
        const size_t ebase = (size_t)e * DIM * HID;
#pragma unroll
        for (int h = 0; h < 2; ++h)
            pB_[h] = w2b + ebase + (size_t)(nt * 256 + h * 128 + rS) * HID + kcS * 8;
    }

#pragma unroll
    for (int i = 0; i < 4; ++i)
#pragma unroll
        for (int j = 0; j < 4; ++j) acc[i][j] = (ffrag)0.f;

#define SGA2(DB, SUB, TT) do { if ((TT) < NT2) \
        gld16(pA_ + (TT) * 64 + (SUB) * 32, lA + (DB) * 8192 + (SUB) * 4096 + wid512); } while (0)
#define SGB2(DB, HH, SUB, TT) do { if ((TT) < NT2) \
        gld16(pB_[HH] + (TT) * 64 + (SUB) * 32, lB + (DB) * 16384 + (HH) * 8192 + (SUB) * 4096 + wid512); } while (0)
#define RDB2(DB) do { _Pragma("unroll") for (int j = 0; j < 4; ++j) { \
        br[j][0] = *(const bfrag*)&lB[(DB) * 16384 + boff[j]]; \
        br[j][1] = *(const bfrag*)&lB[(DB) * 16384 + boff[j] + 4096]; } } while (0)
#define RDA2(DB, S) do { _Pragma("unroll") for (int i = 0; i < 4; ++i) \
        a[i] = *(const bfrag*)&lA[(DB) * 8192 + (S) * 4096 + aoff[i]]; } while (0)
#define MM2(S) do { __builtin_amdgcn_s_setprio(1); \
        _Pragma("unroll") for (int i = 0; i < 4; ++i) \
        _Pragma("unroll") for (int j = 0; j < 4; ++j) \
            acc[i][j] = __builtin_amdgcn_mfma_f32_16x16x32_bf16(a[i], br[j][S], acc[i][j], 0, 0, 0); \
        __builtin_amdgcn_s_setprio(0); } while (0)

    // prologue: T0 full (6 sweeps) + T1.B 3 sweeps; vmcnt(3)
    SGA2(0, 0, 0); SGA2(0, 1, 0);
    SGB2(0, 0, 0, 0); SGB2(0, 0, 1, 0); SGB2(0, 1, 0, 0); SGB2(0, 1, 1, 0);
    SGB2(1, 0, 0, 1); SGB2(1, 0, 1, 1); SGB2(1, 1, 0, 1);
    WAITVM(3);
    BARRIER();

#pragma unroll 1
    for (int it = 0; it < NT2 / 2; ++it) {
        const int t1 = 2 * it + 1, t2 = 2 * it + 2, t3 = 2 * it + 3;
        const bool last = (it == NT2 / 2 - 1);
        // P1
        RDB2(0); RDA2(0, 0);
        SGB2(1, 1, 1, t1); SGA2(1, 0, t1); SGA2(1, 1, t1);
        BARRIER(); MM2(0); BARRIER();
        // P2
        RDA2(0, 1);
        SGB2(0, 0, 0, t2); SGB2(0, 0, 1, t2); SGB2(0, 1, 0, t2);
        if (last) { WAITVM(0); } else { WAITVM(3); }
        BARRIER(); MM2(1); BARRIER();
        // P3
        RDB2(1); RDA2(1, 0);
        SGB2(0, 1, 1, t2); SGA2(0, 0, t2); SGA2(0, 1, t2);
        BARRIER(); MM2(0); BARRIER();
        // P4
        RDA2(1, 1);
        SGB2(1, 0, 0, t3); SGB2(1, 0, 1, t3); SGB2(1, 1, 0, t3);
        if (last) { WAITVM(0); } else { WAITVM(3); }
        BARRIER(); MM2(1); BARRIER();
    }
#undef MM2
#undef RDA2
#undef RDB2
#undef SGB2
#undef SGA2

    // epilogue: plain coalesced f32 stores of partials (weights applied in combine)
#pragma unroll
    for (int i = 0; i < 4; ++i) {
        int rbase = mw * 64 + i * 16 + ((lane >> 4) << 2);
#pragma unroll
        for (int q = 0; q < 4; ++q) {
            int rl = rbase + q;
            if (rl >= nrows) continue;
            size_t rowoff = (size_t)(m0 + rl) * DIM;
#pragma unroll
            for (int j = 0; j < 4; ++j) {
                int col = nt * 256 + wn + j * 16 + l15;
                H2[rowoff + col] = acc[i][j][q];
            }
        }
    }
}

extern "C" void kernel_launch(void* const* d_in, const int* in_sizes, int n_in,
                              void* d_out, int out_size, void* d_ws, size_t ws_size,
                              hipStream_t stream) {
    const float* x  = (const float*)d_in[0];
    const float* gw = (const float*)d_in[1];
    const float* w1 = (const float*)d_in[2];
    const float* w2 = (const float*)d_in[3];   // dict order: x, gate_w, w1, w2, w3 !
    const float* w3 = (const float*)d_in[4];
    float* out = (float*)d_out;

    char* ws = (char*)d_ws;
    int*    topi    = (int*)(ws + 0);              // 64 KB
    float*  topw    = (float*)(ws + 65536);        // 64 KB
    int*    perm    = (int*)(ws + 131072);         // 64 KB
    float*  pw      = (float*)(ws + 196608);       // 64 KB
    int*    tokslot = (int*)(ws + 262144);         // 64 KB
    int*    counts  = (int*)(ws + 327680);
    int*    offs    = (int*)(ws + 327680 + 256);
    int*    cursor  = (int*)(ws + 327680 + 512);
    int*    nd256   = (int*)(ws + 327680 + 768);
    int*    nd128   = (int*)(ws + 327680 + 772);
    int*    desc256 = (int*)(ws + 327680 + 1024);  // <= ~80 entries
    int*    desc128 = (int*)(ws + 327680 + 2048);  // <= ~140 entries

    const size_t OFF_XB = 655360;                       // xb: 16 MiB
    const size_t OFF_H  = OFF_XB + 16777216;            // H : 128 MiB (bf16 16384x4096)
    const size_t OFF_WA = OFF_H + 134217728;            // w1b, later w2b: 64 MiB
    const size_t OFF_WB = OFF_WA + 67108864;            // w3b, later H2 (f32 16384x1024): 64 MiB

    ushort* xb  = (ushort*)(ws + OFF_XB);
    ushort* H   = (ushort*)(ws + OFF_H);
    ushort* wA  = (ushort*)(ws + OFF_WA);
    ushort* wB  = (ushort*)(ws + OFF_WB);
    float*  H2  = (float*)(ws + OFF_WB);                // reuses w3b slot after ffn1

    hipMemsetAsync(counts, 0, 32, stream);

    k_router<<<dim3(TK / 4), 256, 0, stream>>>(x, gw, topi, topw);
    k_count<<<dim3((2 * TK) / 256), 256, 0, stream>>>(topi, counts);
    k_scan<<<dim3(1), 64, 0, stream>>>(counts, offs, cursor, desc256, nd256, desc128, nd128);
    k_scatter<<<dim3(TK / 256), 256, 0, stream>>>(topi, topw, cursor, perm, pw, tokslot);

    k_cvt<<<dim3((TK * DIM / 8) / 256), 256, 0, stream>>>(x, xb, TK * DIM / 8);
    k_cvt<<<dim3((NE * HID * DIM / 8) / 256), 256, 0, stream>>>(w1, wA, NE * HID * DIM / 8);
    k_cvt<<<dim3((NE * HID * DIM / 8) / 256), 256, 0, stream>>>(w3, wB, NE * HID * DIM / 8);

    // grid: q<=8 (worst-case 71 descs) x 32 nt x 8 xcd
    k_ffn1<<<dim3(9 * 256), 512, 0, stream>>>(xb, wA, wB, offs, perm, desc256, nd256, H);

    // w1b dead now; reuse its slot for w2b
    k_cvt<<<dim3((NE * DIM * HID / 8) / 256), 256, 0, stream>>>(w2, wA, NE * DIM * HID / 8);

    // grid: q<=16 (worst-case 135 descs) x 4 nt x 8 xcd ; writes H2 over w3b slot
    k_ffn2<<<dim3(17 * 32), 512, 0, stream>>>(H, wA, offs, desc128, nd128, H2);

    k_combine<<<dim3(TK), 256, 0, stream>>>(H2, tokslot, pw, out);
}